// Round 7
// baseline (181.093 us; speedup 1.0000x reference)
//
#include <hip/hip_runtime.h>
#include <hip/hip_bf16.h>

typedef unsigned short ushort_t;
typedef __attribute__((ext_vector_type(4))) float f32x4;
typedef __attribute__((ext_vector_type(8))) __bf16 bfrag;

#define MFMA16(a,b,c) __builtin_amdgcn_mfma_f32_16x16x32_bf16((a),(b),(c),0,0,0)

#define HID 768
#define NH 12
#define SEQ 4096
#define QSCALE 0.18033688011112042f  /* 0.125 * log2(e): folds 1/sqrt(64) and exp->exp2 */

// Per-wave drain of outstanding global_load_lds BEFORE a barrier.
// __syncthreads() alone does NOT guarantee another wave's LDS-DMA has landed:
// vmcnt is per-wave and the waitcnt pass only protects same-wave reads.
#define DRAIN_VMEM() asm volatile("s_waitcnt vmcnt(0)" ::: "memory")

__device__ __forceinline__ unsigned short f2bf(float x) {
  union { float f; unsigned u; } v; v.f = x;
  unsigned r = v.u + 0x7fffu + ((v.u >> 16) & 1u);  // RTNE
  return (unsigned short)(r >> 16);
}

typedef const unsigned char __attribute__((address_space(1)))* gas1_t;
typedef unsigned char __attribute__((address_space(3)))* las3_t;
__device__ __forceinline__ void gload_lds16(const void* g, void* l) {
  __builtin_amdgcn_global_load_lds((gas1_t)(unsigned long long)g,
                                   (las3_t)(unsigned)(unsigned long long)l,
                                   16, 0, 0);
}

__device__ __forceinline__ f32x4 zero4() { f32x4 z = {0.f, 0.f, 0.f, 0.f}; return z; }

// ---------------------------------------------------------------- kernel 1
__global__ __launch_bounds__(256) void cvt_hidden(const float* __restrict__ hs,
                                                  ushort_t* __restrict__ A) {
  int i = blockIdx.x * 256 + threadIdx.x;
  float4 v = ((const float4*)hs)[i];
  ushort4 o;
  o.x = f2bf(v.x); o.y = f2bf(v.y); o.z = f2bf(v.z); o.w = f2bf(v.w);
  ((ushort4*)A)[i] = o;
}

// ---------------------------------------------------------------- kernel 2
__global__ __launch_bounds__(256) void transpose_w(const float* __restrict__ Wq,
                                                   const float* __restrict__ Wk,
                                                   const float* __restrict__ Wv,
                                                   ushort_t* __restrict__ Wt) {
  const int z = blockIdx.z;
  const float* W = (z == 0) ? Wq : ((z == 1) ? Wk : Wv);
  const int k0 = blockIdx.x * 64, n0 = blockIdx.y * 64;
  __shared__ float tile[64][65];
  const int t = threadIdx.x;
  const int c4 = (t & 15) * 4;
  const int r = t >> 4;
#pragma unroll
  for (int it = 0; it < 4; ++it) {
    int rr = r + it * 16;
    float4 v = *(const float4*)&W[(size_t)(k0 + rr) * HID + n0 + c4];
    tile[c4 + 0][rr] = v.x; tile[c4 + 1][rr] = v.y;
    tile[c4 + 2][rr] = v.z; tile[c4 + 3][rr] = v.w;
  }
  __syncthreads();
#pragma unroll
  for (int it = 0; it < 4; ++it) {
    int nl = r + it * 16;
    ushort4 o;
    o.x = f2bf(tile[nl][c4 + 0]); o.y = f2bf(tile[nl][c4 + 1]);
    o.z = f2bf(tile[nl][c4 + 2]); o.w = f2bf(tile[nl][c4 + 3]);
    *(ushort4*)&Wt[((size_t)z * HID + n0 + nl) * HID + k0 + c4] = o;
  }
}

// ---------------------------------------------------------------- kernel 3
// V epilogue stores k-columns permuted within each 32-block:
// V_true col (32K + 16A + 4G + B) stored at (32K + 8G + 4A + B), matching the
// natural in-register k-order of the attn P fragments.  Bijective, zero cost.
__global__ __launch_bounds__(256) void qkv_gemm(const ushort_t* __restrict__ A,
                                                const ushort_t* __restrict__ Wt,
                                                const float* __restrict__ bq,
                                                const float* __restrict__ bk,
                                                const float* __restrict__ bv,
                                                ushort_t* __restrict__ Qh,
                                                ushort_t* __restrict__ Kh,
                                                ushort_t* __restrict__ Vt) {
  __shared__ ushort_t Als[128 * 64];
  __shared__ ushort_t Bls[128 * 64];
  const int z = blockIdx.z;
  const int m0 = blockIdx.x * 128, n0 = blockIdx.y * 128;
  const ushort_t* Wz = Wt + (size_t)z * HID * HID;
  const float* bias = (z == 0) ? bq : ((z == 1) ? bk : bv);
  const int t = threadIdx.x, w = t >> 6, lane = t & 63;
  const int g = lane >> 4, qc = lane & 15;
  const int srow = lane >> 3, sch = lane & 7;
  const int wm = w >> 1, wn = w & 1;

  f32x4 acc[4][4];
#pragma unroll
  for (int mt = 0; mt < 4; ++mt)
#pragma unroll
    for (int nt = 0; nt < 4; ++nt) acc[mt][nt] = zero4();

  for (int kt = 0; kt < 12; ++kt) {
    const int k0 = kt * 64;
#pragma unroll
    for (int i = 0; i < 4; ++i) {
      int row = w * 32 + i * 8 + srow;
      int chA = sch ^ (srow & 7);
      gload_lds16(&A[(size_t)(m0 + row) * HID + k0 + chA * 8],
                  &Als[(w * 32 + i * 8) * 64]);
      gload_lds16(&Wz[(size_t)(n0 + row) * HID + k0 + chA * 8],
                  &Bls[(w * 32 + i * 8) * 64]);
    }
    DRAIN_VMEM();      // all of THIS wave's DMA landed; barrier makes it global
    __syncthreads();
#pragma unroll
    for (int kk = 0; kk < 2; ++kk) {
      bfrag af[4], bf_[4];
#pragma unroll
      for (int mt = 0; mt < 4; ++mt) {
        int row = wm * 64 + mt * 16 + qc;
        af[mt] = *(const bfrag*)((const char*)Als + row * 128 +
                                 (((kk * 4 + g) ^ (qc & 7)) << 4));
      }
#pragma unroll
      for (int nt = 0; nt < 4; ++nt) {
        int row = wn * 64 + nt * 16 + qc;
        bf_[nt] = *(const bfrag*)((const char*)Bls + row * 128 +
                                  (((kk * 4 + g) ^ (qc & 7)) << 4));
      }
#pragma unroll
      for (int mt = 0; mt < 4; ++mt)
#pragma unroll
        for (int nt = 0; nt < 4; ++nt)
          acc[mt][nt] = MFMA16(af[mt], bf_[nt], acc[mt][nt]);
    }
    __syncthreads();
  }

#pragma unroll
  for (int mt = 0; mt < 4; ++mt) {
#pragma unroll
    for (int nt = 0; nt < 4; ++nt) {
      int n = n0 + wn * 64 + nt * 16 + qc;
      int head = n >> 6, d = n & 63;
      float bb = bias[n];
      int mB = m0 + wm * 64 + mt * 16 + 4 * g;
      int bidx = mB >> 12, s0 = mB & 4095;
      f32x4 a = acc[mt][nt];
      if (z == 2) {
        ushort4 o;
        o.x = f2bf(a[0] + bb); o.y = f2bf(a[1] + bb);
        o.z = f2bf(a[2] + bb); o.w = f2bf(a[3] + bb);
        // permuted storage column: (32K|16A|4G|B) -> (32K|8G|4A|B); B=0 here
        int scol = (s0 & ~31) | (((s0 >> 2) & 3) << 3) | (((s0 >> 4) & 1) << 2);
        *(ushort4*)&Vt[((size_t)((bidx * NH + head) * 64 + d)) * SEQ + scol] = o;
      } else {
        ushort_t* dst = (z == 0) ? Qh : Kh;
        float sc = (z == 0) ? QSCALE : 1.0f;
        size_t base = (size_t)(bidx * NH + head) * SEQ;
#pragma unroll
        for (int i = 0; i < 4; ++i)
          dst[(base + s0 + i) * 64 + d] = f2bf((a[i] + bb) * sc);
      }
    }
  }
}

// ---------------------------------------------------------------- kernel 4
// Flash attention, no-max softmax, zero-shuffle P (V-permutation supplies
// the k-order the in-register P fragments carry).  Round-7 change: QBLK=64
// per wave (4 qf), 2-wave blocks (128 q/block) -> grid stays 768 (3/CU)
// while the SAME 16 LDS frag-reads + staging per wave-kt now feed 72 MFMA
// instead of 36 (K/V fragments register-shared across all 4 qf).
// Sync discipline (validated round 6): per-wave vmcnt(0) drain before every
// handoff barrier; no staging issued on the last iteration.
__global__ __launch_bounds__(128, 2) void attn_kernel(const ushort_t* __restrict__ Qh,
                                                      const ushort_t* __restrict__ Kh,
                                                      const ushort_t* __restrict__ Vt,
                                                      float* __restrict__ out) {
  const int bh = blockIdx.y;
  const int b = bh / NH, head = bh - b * NH;
  const int t = threadIdx.x, w = t >> 6, lane = t & 63;
  const int g = lane >> 4, qc = lane & 15;
  const ushort_t* Qb = Qh + (size_t)bh * SEQ * 64;
  const ushort_t* Kb = Kh + (size_t)bh * SEQ * 64;
  const ushort_t* Vb = Vt + (size_t)bh * 64 * SEQ;
  const int q0 = blockIdx.x * 128 + w * 64;

  __shared__ ushort_t Kls[2][4096];  // [buf][64 krow x 64 d], (r&7)-swizzled 16B chunks
  __shared__ ushort_t Vls[2][4096];  // [buf][64 d x 64 k],   (r&7)-swizzled 16B chunks

  // staging map: 2 waves x 64 lanes x 4 chunks = 512 chunks = one 8KB tile
  int jr[4], jc[4];
#pragma unroll
  for (int i = 0; i < 4; ++i) {
    int j = w * 256 + i * 64 + lane;
    jr[i] = j >> 3;
    jc[i] = (j & 7) ^ (jr[i] & 7);
  }

  bfrag qv[4][2];
#pragma unroll
  for (int qf = 0; qf < 4; ++qf)
#pragma unroll
    for (int dd = 0; dd < 2; ++dd)
      qv[qf][dd] = *(const bfrag*)&Qb[(size_t)(q0 + qf * 16 + qc) * 64 + dd * 32 + g * 8];

  f32x4 o[4][4];
  f32x4 lacc[4];
#pragma unroll
  for (int qf = 0; qf < 4; ++qf) {
    lacc[qf] = zero4();
#pragma unroll
    for (int dt = 0; dt < 4; ++dt) o[qf][dt] = zero4();
  }
  bfrag ones;
#pragma unroll
  for (int j = 0; j < 8; ++j) ones[j] = (__bf16)1.0f;

  // prologue: stage tile 0 into buf 0
#pragma unroll
  for (int i = 0; i < 4; ++i) {
    gload_lds16(&Kb[(size_t)jr[i] * 64 + jc[i] * 8], &Kls[0][(w * 256 + i * 64) * 8]);
    gload_lds16(&Vb[(size_t)jr[i] * SEQ + jc[i] * 8], &Vls[0][(w * 256 + i * 64) * 8]);
  }

  for (int kt = 0; kt < 64; ++kt) {
    const int cur = kt & 1;
    DRAIN_VMEM();     // THIS wave's staging (prev iter / prologue) has landed
    __syncthreads();  // ... and now everyone's has: buf `cur` fully staged
    if (kt < 63) {    // no staging on last iter: nothing in flight at s_endpgm
      const int kbn = (kt + 1) * 64;
#pragma unroll
      for (int i = 0; i < 4; ++i) {
        gload_lds16(&Kb[(size_t)(kbn + jr[i]) * 64 + jc[i] * 8],
                    &Kls[cur ^ 1][(w * 256 + i * 64) * 8]);
        gload_lds16(&Vb[(size_t)jr[i] * SEQ + kbn + jc[i] * 8],
                    &Vls[cur ^ 1][(w * 256 + i * 64) * 8]);
      }
    }
    const ushort_t* Kc = Kls[cur];
    const ushort_t* Vc = Vls[cur];

    // K fragments (round-2-validated addresses), shared by all 4 qf
    bfrag ak[4][2];
#pragma unroll
    for (int s = 0; s < 4; ++s) {
      const int r = s * 16 + qc;
      ak[s][0] = *(const bfrag*)&Kc[r * 64 + ((g ^ (qc & 7)) * 8)];
      ak[s][1] = *(const bfrag*)&Kc[r * 64 + (((4 + g) ^ (qc & 7)) * 8)];
    }

    // S^T slabs -> P fragments, fully in-register (natural k-order)
    bfrag bpq[4][2];
#pragma unroll
    for (int qf = 0; qf < 4; ++qf) {
      f32x4 st[4];
      __builtin_amdgcn_s_setprio(1);
#pragma unroll
      for (int s = 0; s < 4; ++s) {
        f32x4 zz = zero4();
        zz = MFMA16(ak[s][0], qv[qf][0], zz);
        st[s] = MFMA16(ak[s][1], qv[qf][1], zz);
      }
      __builtin_amdgcn_s_setprio(0);
#pragma unroll
      for (int i = 0; i < 4; ++i) {
        bpq[qf][0][i]     = (__bf16)__builtin_amdgcn_exp2f(st[0][i]);
        bpq[qf][0][4 + i] = (__bf16)__builtin_amdgcn_exp2f(st[1][i]);
        bpq[qf][1][i]     = (__bf16)__builtin_amdgcn_exp2f(st[2][i]);
        bpq[qf][1][4 + i] = (__bf16)__builtin_amdgcn_exp2f(st[3][i]);
      }
      lacc[qf] = MFMA16(ones, bpq[qf][0], lacc[qf]);
      lacc[qf] = MFMA16(ones, bpq[qf][1], lacc[qf]);
    }

    // O^T += Vperm.P^T   (av read once, shared by all 4 qf)
    __builtin_amdgcn_s_setprio(1);
#pragma unroll
    for (int kk = 0; kk < 2; ++kk) {
#pragma unroll
      for (int dt = 0; dt < 4; ++dt) {
        bfrag av = *(const bfrag*)&Vc[(dt * 16 + qc) * 64 + (((kk * 4 + g) ^ (qc & 7)) * 8)];
#pragma unroll
        for (int qf = 0; qf < 4; ++qf)
          o[qf][dt] = MFMA16(av, bpq[qf][kk], o[qf][dt]);
      }
    }
    __builtin_amdgcn_s_setprio(0);
  }

  // epilogue: O^T layout row d = dt*16+4g+i, col q = qc; l identical in every reg
#pragma unroll
  for (int qf = 0; qf < 4; ++qf) {
    float inv = 1.0f / lacc[qf][0];
    int qrow = q0 + qf * 16 + qc;
    float* orow = out + (size_t)(b * SEQ + qrow) * HID + head * 64;
#pragma unroll
    for (int dt = 0; dt < 4; ++dt) {
      float4 vv;
      vv.x = o[qf][dt][0] * inv; vv.y = o[qf][dt][1] * inv;
      vv.z = o[qf][dt][2] * inv; vv.w = o[qf][dt][3] * inv;
      *(float4*)(orow + dt * 16 + 4 * g) = vv;
    }
  }
}

// ---------------------------------------------------------------- launch
extern "C" void kernel_launch(void* const* d_in, const int* in_sizes, int n_in,
                              void* d_out, int out_size, void* d_ws, size_t ws_size,
                              hipStream_t stream) {
  (void)in_sizes; (void)n_in; (void)out_size; (void)ws_size;
  const float* hs = (const float*)d_in[0];
  const float* Wq = (const float*)d_in[1];
  const float* bq = (const float*)d_in[2];
  const float* Wk = (const float*)d_in[3];
  const float* bk = (const float*)d_in[4];
  const float* Wv = (const float*)d_in[5];
  const float* bv = (const float*)d_in[6];
  float* out = (float*)d_out;

  char* ws = (char*)d_ws;
  ushort_t* Abf = (ushort_t*)ws;                               // 12582912 B
  ushort_t* Wt  = (ushort_t*)(ws + 12582912);                  //  3538944 B
  ushort_t* Qh  = (ushort_t*)(ws + 12582912 + 3538944);        // 12582912 B
  ushort_t* Kh  = Qh + 6291456;
  ushort_t* Vt  = Kh + 6291456;

  cvt_hidden<<<6144, 256, 0, stream>>>(hs, Abf);
  transpose_w<<<dim3(12, 12, 3), 256, 0, stream>>>(Wq, Wk, Wv, Wt);
  qkv_gemm<<<dim3(64, 6, 3), 256, 0, stream>>>(Abf, Wt, bq, bk, bv, Qh, Kh, Vt);
  attn_kernel<<<dim3(32, 24), 128, 0, stream>>>(Qh, Kh, Vt, out);
}

// Round 8
// 174.439 us; speedup vs baseline: 1.0382x; 1.0382x over previous
//
#include <hip/hip_runtime.h>
#include <hip/hip_bf16.h>

typedef unsigned short ushort_t;
typedef __attribute__((ext_vector_type(4))) float f32x4;
typedef __attribute__((ext_vector_type(8))) __bf16 bfrag;

#define MFMA16(a,b,c) __builtin_amdgcn_mfma_f32_16x16x32_bf16((a),(b),(c),0,0,0)

#define HID 768
#define NH 12
#define SEQ 4096
#define QSCALE 0.18033688011112042f  /* 0.125 * log2(e): folds 1/sqrt(64) and exp->exp2 */

// Per-wave drain of outstanding global_load_lds BEFORE a barrier.
// __syncthreads() alone does NOT guarantee another wave's LDS-DMA has landed:
// vmcnt is per-wave and the waitcnt pass only protects same-wave reads.
#define DRAIN_VMEM() asm volatile("s_waitcnt vmcnt(0)" ::: "memory")

__device__ __forceinline__ unsigned short f2bf(float x) {
  union { float f; unsigned u; } v; v.f = x;
  unsigned r = v.u + 0x7fffu + ((v.u >> 16) & 1u);  // RTNE
  return (unsigned short)(r >> 16);
}

typedef const unsigned char __attribute__((address_space(1)))* gas1_t;
typedef unsigned char __attribute__((address_space(3)))* las3_t;
__device__ __forceinline__ void gload_lds16(const void* g, void* l) {
  __builtin_amdgcn_global_load_lds((gas1_t)(unsigned long long)g,
                                   (las3_t)(unsigned)(unsigned long long)l,
                                   16, 0, 0);
}

__device__ __forceinline__ f32x4 zero4() { f32x4 z = {0.f, 0.f, 0.f, 0.f}; return z; }

// ---------------------------------------------------------------- kernel 1
__global__ __launch_bounds__(256) void cvt_hidden(const float* __restrict__ hs,
                                                  ushort_t* __restrict__ A) {
  int i = blockIdx.x * 256 + threadIdx.x;
  float4 v = ((const float4*)hs)[i];
  ushort4 o;
  o.x = f2bf(v.x); o.y = f2bf(v.y); o.z = f2bf(v.z); o.w = f2bf(v.w);
  ((ushort4*)A)[i] = o;
}

// ---------------------------------------------------------------- kernel 2
__global__ __launch_bounds__(256) void transpose_w(const float* __restrict__ Wq,
                                                   const float* __restrict__ Wk,
                                                   const float* __restrict__ Wv,
                                                   ushort_t* __restrict__ Wt) {
  const int z = blockIdx.z;
  const float* W = (z == 0) ? Wq : ((z == 1) ? Wk : Wv);
  const int k0 = blockIdx.x * 64, n0 = blockIdx.y * 64;
  __shared__ float tile[64][65];
  const int t = threadIdx.x;
  const int c4 = (t & 15) * 4;
  const int r = t >> 4;
#pragma unroll
  for (int it = 0; it < 4; ++it) {
    int rr = r + it * 16;
    float4 v = *(const float4*)&W[(size_t)(k0 + rr) * HID + n0 + c4];
    tile[c4 + 0][rr] = v.x; tile[c4 + 1][rr] = v.y;
    tile[c4 + 2][rr] = v.z; tile[c4 + 3][rr] = v.w;
  }
  __syncthreads();
#pragma unroll
  for (int it = 0; it < 4; ++it) {
    int nl = r + it * 16;
    ushort4 o;
    o.x = f2bf(tile[nl][c4 + 0]); o.y = f2bf(tile[nl][c4 + 1]);
    o.z = f2bf(tile[nl][c4 + 2]); o.w = f2bf(tile[nl][c4 + 3]);
    *(ushort4*)&Wt[((size_t)z * HID + n0 + nl) * HID + k0 + c4] = o;
  }
}

// ---------------------------------------------------------------- kernel 3
// V epilogue stores k-columns permuted within each 32-block:
// V_true col (32K + 16A + 4G + B) stored at (32K + 8G + 4A + B), matching the
// natural in-register k-order of the attn P fragments.  Bijective, zero cost.
__global__ __launch_bounds__(256) void qkv_gemm(const ushort_t* __restrict__ A,
                                                const ushort_t* __restrict__ Wt,
                                                const float* __restrict__ bq,
                                                const float* __restrict__ bk,
                                                const float* __restrict__ bv,
                                                ushort_t* __restrict__ Qh,
                                                ushort_t* __restrict__ Kh,
                                                ushort_t* __restrict__ Vt) {
  __shared__ ushort_t Als[128 * 64];
  __shared__ ushort_t Bls[128 * 64];
  const int z = blockIdx.z;
  const int m0 = blockIdx.x * 128, n0 = blockIdx.y * 128;
  const ushort_t* Wz = Wt + (size_t)z * HID * HID;
  const float* bias = (z == 0) ? bq : ((z == 1) ? bk : bv);
  const int t = threadIdx.x, w = t >> 6, lane = t & 63;
  const int g = lane >> 4, qc = lane & 15;
  const int srow = lane >> 3, sch = lane & 7;
  const int wm = w >> 1, wn = w & 1;

  f32x4 acc[4][4];
#pragma unroll
  for (int mt = 0; mt < 4; ++mt)
#pragma unroll
    for (int nt = 0; nt < 4; ++nt) acc[mt][nt] = zero4();

  for (int kt = 0; kt < 12; ++kt) {
    const int k0 = kt * 64;
#pragma unroll
    for (int i = 0; i < 4; ++i) {
      int row = w * 32 + i * 8 + srow;
      int chA = sch ^ (srow & 7);
      gload_lds16(&A[(size_t)(m0 + row) * HID + k0 + chA * 8],
                  &Als[(w * 32 + i * 8) * 64]);
      gload_lds16(&Wz[(size_t)(n0 + row) * HID + k0 + chA * 8],
                  &Bls[(w * 32 + i * 8) * 64]);
    }
    DRAIN_VMEM();      // all of THIS wave's DMA landed; barrier makes it global
    __syncthreads();
#pragma unroll
    for (int kk = 0; kk < 2; ++kk) {
      bfrag af[4], bf_[4];
#pragma unroll
      for (int mt = 0; mt < 4; ++mt) {
        int row = wm * 64 + mt * 16 + qc;
        af[mt] = *(const bfrag*)((const char*)Als + row * 128 +
                                 (((kk * 4 + g) ^ (qc & 7)) << 4));
      }
#pragma unroll
      for (int nt = 0; nt < 4; ++nt) {
        int row = wn * 64 + nt * 16 + qc;
        bf_[nt] = *(const bfrag*)((const char*)Bls + row * 128 +
                                  (((kk * 4 + g) ^ (qc & 7)) << 4));
      }
#pragma unroll
      for (int mt = 0; mt < 4; ++mt)
#pragma unroll
        for (int nt = 0; nt < 4; ++nt)
          acc[mt][nt] = MFMA16(af[mt], bf_[nt], acc[mt][nt]);
    }
    __syncthreads();
  }

#pragma unroll
  for (int mt = 0; mt < 4; ++mt) {
#pragma unroll
    for (int nt = 0; nt < 4; ++nt) {
      int n = n0 + wn * 64 + nt * 16 + qc;
      int head = n >> 6, d = n & 63;
      float bb = bias[n];
      int mB = m0 + wm * 64 + mt * 16 + 4 * g;
      int bidx = mB >> 12, s0 = mB & 4095;
      f32x4 a = acc[mt][nt];
      if (z == 2) {
        ushort4 o;
        o.x = f2bf(a[0] + bb); o.y = f2bf(a[1] + bb);
        o.z = f2bf(a[2] + bb); o.w = f2bf(a[3] + bb);
        // permuted storage column: (32K|16A|4G|B) -> (32K|8G|4A|B); B=0 here
        int scol = (s0 & ~31) | (((s0 >> 2) & 3) << 3) | (((s0 >> 4) & 1) << 2);
        *(ushort4*)&Vt[((size_t)((bidx * NH + head) * 64 + d)) * SEQ + scol] = o;
      } else {
        ushort_t* dst = (z == 0) ? Qh : Kh;
        float sc = (z == 0) ? QSCALE : 1.0f;
        size_t base = (size_t)(bidx * NH + head) * SEQ;
#pragma unroll
        for (int i = 0; i < 4; ++i)
          dst[(base + s0 + i) * 64 + d] = f2bf((a[i] + bb) * sc);
      }
    }
  }
}

// ---------------------------------------------------------------- kernel 4
// Flash attention, no-max softmax, zero-shuffle P, 2q x 2k wave split.
// Softmax here is max-free, so P/l/O are plain sums over k: wave (qh,kh)
// computes 32 q-rows x its 32-k half of every 64-k tile.  This halves the
// per-wave LDS fragment traffic (8KB/wave-kt; block reads 32KB vs round-6's
// 64KB -- LDS read BW was the co-bottleneck) and doubles blocks (grid 1536,
// ~5/CU by LDS) for 4-5 waves/SIMD latency hiding (round-7 lesson).
// All addresses are the validated round-6 forms restricted to one k-half
// (st slabs, V scol permutation, av chunk (kh*4+g)^(qc&7) == kk=kh).
// Epilogue: kh=1 waves push partial O/l through LDS; kh=0 waves add + store.
// Sync discipline (validated round 6): per-wave vmcnt(0) drain before every
// handoff barrier; no staging issued on the last iteration.
__global__ __launch_bounds__(256, 3) void attn_kernel(const ushort_t* __restrict__ Qh,
                                                      const ushort_t* __restrict__ Kh,
                                                      const ushort_t* __restrict__ Vt,
                                                      float* __restrict__ out) {
  const int bh = blockIdx.y;
  const int b = bh / NH, head = bh - b * NH;
  const int t = threadIdx.x, w = t >> 6, lane = t & 63;
  const int g = lane >> 4, qc = lane & 15;
  const int qh = w >> 1, kh = w & 1;
  const ushort_t* Qb = Qh + (size_t)bh * SEQ * 64;
  const ushort_t* Kb = Kh + (size_t)bh * SEQ * 64;
  const ushort_t* Vb = Vt + (size_t)bh * 64 * SEQ;
  const int q0 = blockIdx.x * 64 + qh * 32;

  __shared__ ushort_t Kls[2][4096];  // [buf][64 krow x 64 d], (r&7)-swizzled 16B chunks
  __shared__ ushort_t Vls[2][4096];  // [buf][64 d x 64 k],   (r&7)-swizzled 16B chunks

  // staging map (unchanged from round 6): 4 waves x 64 lanes x 2 chunks = 512
  int jr[2], jc[2];
#pragma unroll
  for (int i = 0; i < 2; ++i) {
    int j = w * 128 + i * 64 + lane;
    jr[i] = j >> 3;
    jc[i] = (j & 7) ^ (jr[i] & 7);
  }

  bfrag qv[2][2];
#pragma unroll
  for (int qf = 0; qf < 2; ++qf)
#pragma unroll
    for (int dd = 0; dd < 2; ++dd)
      qv[qf][dd] = *(const bfrag*)&Qb[(size_t)(q0 + qf * 16 + qc) * 64 + dd * 32 + g * 8];

  f32x4 o[2][4];
  f32x4 lacc[2];
#pragma unroll
  for (int qf = 0; qf < 2; ++qf) {
    lacc[qf] = zero4();
#pragma unroll
    for (int dt = 0; dt < 4; ++dt) o[qf][dt] = zero4();
  }
  bfrag ones;
#pragma unroll
  for (int j = 0; j < 8; ++j) ones[j] = (__bf16)1.0f;

  // prologue: stage tile 0 into buf 0
#pragma unroll
  for (int i = 0; i < 2; ++i) {
    gload_lds16(&Kb[(size_t)jr[i] * 64 + jc[i] * 8], &Kls[0][(w * 128 + i * 64) * 8]);
    gload_lds16(&Vb[(size_t)jr[i] * SEQ + jc[i] * 8], &Vls[0][(w * 128 + i * 64) * 8]);
  }

  for (int kt = 0; kt < 64; ++kt) {
    const int cur = kt & 1;
    DRAIN_VMEM();     // THIS wave's staging (prev iter / prologue) has landed
    __syncthreads();  // ... and now everyone's has: buf `cur` fully staged
    if (kt < 63) {    // no staging on last iter: nothing in flight at s_endpgm
      const int kbn = (kt + 1) * 64;
#pragma unroll
      for (int i = 0; i < 2; ++i) {
        gload_lds16(&Kb[(size_t)(kbn + jr[i]) * 64 + jc[i] * 8],
                    &Kls[cur ^ 1][(w * 128 + i * 64) * 8]);
        gload_lds16(&Vb[(size_t)jr[i] * SEQ + kbn + jc[i] * 8],
                    &Vls[cur ^ 1][(w * 128 + i * 64) * 8]);
      }
    }
    const ushort_t* Kc = Kls[cur];
    const ushort_t* Vc = Vls[cur];

    // K fragments: this wave's 32-k half (rows kh*32 + s*16 + qc)
    bfrag ak[2][2];
#pragma unroll
    for (int s = 0; s < 2; ++s) {
      const int r = kh * 32 + s * 16 + qc;
      ak[s][0] = *(const bfrag*)&Kc[r * 64 + ((g ^ (qc & 7)) * 8)];
      ak[s][1] = *(const bfrag*)&Kc[r * 64 + (((4 + g) ^ (qc & 7)) * 8)];
    }
    // V fragments: this wave's 32-k half of all 64 d rows
    bfrag av[4];
#pragma unroll
    for (int dt = 0; dt < 4; ++dt)
      av[dt] = *(const bfrag*)&Vc[(dt * 16 + qc) * 64 + (((kh * 4 + g) ^ (qc & 7)) * 8)];

    // S^T slabs -> P fragment (one per qf; k-order matches V scol permutation)
    bfrag bpq[2];
#pragma unroll
    for (int qf = 0; qf < 2; ++qf) {
      f32x4 st[2];
#pragma unroll
      for (int s = 0; s < 2; ++s) {
        f32x4 zz = zero4();
        zz = MFMA16(ak[s][0], qv[qf][0], zz);
        st[s] = MFMA16(ak[s][1], qv[qf][1], zz);
      }
      bfrag p;
#pragma unroll
      for (int i = 0; i < 4; ++i) {
        p[i]     = (__bf16)__builtin_amdgcn_exp2f(st[0][i]);
        p[4 + i] = (__bf16)__builtin_amdgcn_exp2f(st[1][i]);
      }
      bpq[qf] = p;
      lacc[qf] = MFMA16(ones, p, lacc[qf]);
    }

    // O^T += Vperm.P^T  (partial over this wave's k-half)
#pragma unroll
    for (int dt = 0; dt < 4; ++dt) {
      o[0][dt] = MFMA16(av[dt], bpq[0], o[0][dt]);
      o[1][dt] = MFMA16(av[dt], bpq[1], o[1][dt]);
    }
  }

  // ---- cross-kh reduction through LDS (buffers are free now; DMA drained) ----
  __syncthreads();
  float* redO = (float*)&Kls[0][0];   // 16KB: 2 qh x 8 frag x 64 lanes x f32x4
  float* redL = (float*)&Vls[0][0];   // 2 qh x 2 qf x 64 lanes x f32
  if (kh == 1) {
#pragma unroll
    for (int qf = 0; qf < 2; ++qf) {
#pragma unroll
      for (int dt = 0; dt < 4; ++dt)
        *(f32x4*)&redO[qh * 2048 + (qf * 4 + dt) * 256 + lane * 4] = o[qf][dt];
      redL[qh * 128 + qf * 64 + lane] = lacc[qf][0];
    }
  }
  __syncthreads();
  if (kh == 0) {
#pragma unroll
    for (int qf = 0; qf < 2; ++qf) {
      float l = lacc[qf][0] + redL[qh * 128 + qf * 64 + lane];
      float inv = 1.0f / l;
      int qrow = q0 + qf * 16 + qc;
      float* orow = out + (size_t)(b * SEQ + qrow) * HID + head * 64;
#pragma unroll
      for (int dt = 0; dt < 4; ++dt) {
        f32x4 p = *(f32x4*)&redO[qh * 2048 + (qf * 4 + dt) * 256 + lane * 4];
        f32x4 s = o[qf][dt] + p;
        float4 vv;
        vv.x = s[0] * inv; vv.y = s[1] * inv; vv.z = s[2] * inv; vv.w = s[3] * inv;
        *(float4*)(orow + dt * 16 + 4 * g) = vv;
      }
    }
  }
}

// ---------------------------------------------------------------- launch
extern "C" void kernel_launch(void* const* d_in, const int* in_sizes, int n_in,
                              void* d_out, int out_size, void* d_ws, size_t ws_size,
                              hipStream_t stream) {
  (void)in_sizes; (void)n_in; (void)out_size; (void)ws_size;
  const float* hs = (const float*)d_in[0];
  const float* Wq = (const float*)d_in[1];
  const float* bq = (const float*)d_in[2];
  const float* Wk = (const float*)d_in[3];
  const float* bk = (const float*)d_in[4];
  const float* Wv = (const float*)d_in[5];
  const float* bv = (const float*)d_in[6];
  float* out = (float*)d_out;

  char* ws = (char*)d_ws;
  ushort_t* Abf = (ushort_t*)ws;                               // 12582912 B
  ushort_t* Wt  = (ushort_t*)(ws + 12582912);                  //  3538944 B
  ushort_t* Qh  = (ushort_t*)(ws + 12582912 + 3538944);        // 12582912 B
  ushort_t* Kh  = Qh + 6291456;
  ushort_t* Vt  = Kh + 6291456;

  cvt_hidden<<<6144, 256, 0, stream>>>(hs, Abf);
  transpose_w<<<dim3(12, 12, 3), 256, 0, stream>>>(Wq, Wk, Wv, Wt);
  qkv_gemm<<<dim3(64, 6, 3), 256, 0, stream>>>(Abf, Wt, bq, bk, bv, Qh, Kh, Vt);
  attn_kernel<<<dim3(64, 24), 256, 0, stream>>>(Qh, Kh, Vt, out);
}

// Round 9
// 164.474 us; speedup vs baseline: 1.1010x; 1.0606x over previous
//
#include <hip/hip_runtime.h>
#include <hip/hip_bf16.h>

typedef unsigned short ushort_t;
typedef __attribute__((ext_vector_type(4))) float f32x4;
typedef __attribute__((ext_vector_type(8))) __bf16 bfrag;

#define MFMA16(a,b,c) __builtin_amdgcn_mfma_f32_16x16x32_bf16((a),(b),(c),0,0,0)

#define HID 768
#define NH 12
#define SEQ 4096
#define QSCALE 0.18033688011112042f  /* 0.125 * log2(e): folds 1/sqrt(64) and exp->exp2 */

// Per-wave drain of outstanding global_load_lds BEFORE a barrier.
// __syncthreads() alone does NOT guarantee another wave's LDS-DMA has landed:
// vmcnt is per-wave and the waitcnt pass only protects same-wave reads.
#define DRAIN_VMEM() asm volatile("s_waitcnt vmcnt(0)" ::: "memory")

__device__ __forceinline__ unsigned short f2bf(float x) {
  union { float f; unsigned u; } v; v.f = x;
  unsigned r = v.u + 0x7fffu + ((v.u >> 16) & 1u);  // RTNE
  return (unsigned short)(r >> 16);
}

typedef const unsigned char __attribute__((address_space(1)))* gas1_t;
typedef unsigned char __attribute__((address_space(3)))* las3_t;
__device__ __forceinline__ void gload_lds16(const void* g, void* l) {
  __builtin_amdgcn_global_load_lds((gas1_t)(unsigned long long)g,
                                   (las3_t)(unsigned)(unsigned long long)l,
                                   16, 0, 0);
}

__device__ __forceinline__ f32x4 zero4() { f32x4 z = {0.f, 0.f, 0.f, 0.f}; return z; }

// ---------------------------------------------------------------- kernel 1
__global__ __launch_bounds__(256) void cvt_hidden(const float* __restrict__ hs,
                                                  ushort_t* __restrict__ A) {
  int i = blockIdx.x * 256 + threadIdx.x;
  float4 v = ((const float4*)hs)[i];
  ushort4 o;
  o.x = f2bf(v.x); o.y = f2bf(v.y); o.z = f2bf(v.z); o.w = f2bf(v.w);
  ((ushort4*)A)[i] = o;
}

// ---------------------------------------------------------------- kernel 2
__global__ __launch_bounds__(256) void transpose_w(const float* __restrict__ Wq,
                                                   const float* __restrict__ Wk,
                                                   const float* __restrict__ Wv,
                                                   ushort_t* __restrict__ Wt) {
  const int z = blockIdx.z;
  const float* W = (z == 0) ? Wq : ((z == 1) ? Wk : Wv);
  const int k0 = blockIdx.x * 64, n0 = blockIdx.y * 64;
  __shared__ float tile[64][65];
  const int t = threadIdx.x;
  const int c4 = (t & 15) * 4;
  const int r = t >> 4;
#pragma unroll
  for (int it = 0; it < 4; ++it) {
    int rr = r + it * 16;
    float4 v = *(const float4*)&W[(size_t)(k0 + rr) * HID + n0 + c4];
    tile[c4 + 0][rr] = v.x; tile[c4 + 1][rr] = v.y;
    tile[c4 + 2][rr] = v.z; tile[c4 + 3][rr] = v.w;
  }
  __syncthreads();
#pragma unroll
  for (int it = 0; it < 4; ++it) {
    int nl = r + it * 16;
    ushort4 o;
    o.x = f2bf(tile[nl][c4 + 0]); o.y = f2bf(tile[nl][c4 + 1]);
    o.z = f2bf(tile[nl][c4 + 2]); o.w = f2bf(tile[nl][c4 + 3]);
    *(ushort4*)&Wt[((size_t)z * HID + n0 + nl) * HID + k0 + c4] = o;
  }
}

// ---------------------------------------------------------------- kernel 3
// V epilogue stores k-columns permuted within each 32-block:
// V_true col (32K + 16A + 4G + B) stored at (32K + 8G + 4A + B), matching the
// natural in-register k-order of the attn P fragments.  Bijective, zero cost.
__global__ __launch_bounds__(256) void qkv_gemm(const ushort_t* __restrict__ A,
                                                const ushort_t* __restrict__ Wt,
                                                const float* __restrict__ bq,
                                                const float* __restrict__ bk,
                                                const float* __restrict__ bv,
                                                ushort_t* __restrict__ Qh,
                                                ushort_t* __restrict__ Kh,
                                                ushort_t* __restrict__ Vt) {
  __shared__ ushort_t Als[128 * 64];
  __shared__ ushort_t Bls[128 * 64];
  const int z = blockIdx.z;
  const int m0 = blockIdx.x * 128, n0 = blockIdx.y * 128;
  const ushort_t* Wz = Wt + (size_t)z * HID * HID;
  const float* bias = (z == 0) ? bq : ((z == 1) ? bk : bv);
  const int t = threadIdx.x, w = t >> 6, lane = t & 63;
  const int g = lane >> 4, qc = lane & 15;
  const int srow = lane >> 3, sch = lane & 7;
  const int wm = w >> 1, wn = w & 1;

  f32x4 acc[4][4];
#pragma unroll
  for (int mt = 0; mt < 4; ++mt)
#pragma unroll
    for (int nt = 0; nt < 4; ++nt) acc[mt][nt] = zero4();

  for (int kt = 0; kt < 12; ++kt) {
    const int k0 = kt * 64;
#pragma unroll
    for (int i = 0; i < 4; ++i) {
      int row = w * 32 + i * 8 + srow;
      int chA = sch ^ (srow & 7);
      gload_lds16(&A[(size_t)(m0 + row) * HID + k0 + chA * 8],
                  &Als[(w * 32 + i * 8) * 64]);
      gload_lds16(&Wz[(size_t)(n0 + row) * HID + k0 + chA * 8],
                  &Bls[(w * 32 + i * 8) * 64]);
    }
    DRAIN_VMEM();      // all of THIS wave's DMA landed; barrier makes it global
    __syncthreads();
#pragma unroll
    for (int kk = 0; kk < 2; ++kk) {
      bfrag af[4], bf_[4];
#pragma unroll
      for (int mt = 0; mt < 4; ++mt) {
        int row = wm * 64 + mt * 16 + qc;
        af[mt] = *(const bfrag*)((const char*)Als + row * 128 +
                                 (((kk * 4 + g) ^ (qc & 7)) << 4));
      }
#pragma unroll
      for (int nt = 0; nt < 4; ++nt) {
        int row = wn * 64 + nt * 16 + qc;
        bf_[nt] = *(const bfrag*)((const char*)Bls + row * 128 +
                                  (((kk * 4 + g) ^ (qc & 7)) << 4));
      }
#pragma unroll
      for (int mt = 0; mt < 4; ++mt)
#pragma unroll
        for (int nt = 0; nt < 4; ++nt)
          acc[mt][nt] = MFMA16(af[mt], bf_[nt], acc[mt][nt]);
    }
    __syncthreads();
  }

#pragma unroll
  for (int mt = 0; mt < 4; ++mt) {
#pragma unroll
    for (int nt = 0; nt < 4; ++nt) {
      int n = n0 + wn * 64 + nt * 16 + qc;
      int head = n >> 6, d = n & 63;
      float bb = bias[n];
      int mB = m0 + wm * 64 + mt * 16 + 4 * g;
      int bidx = mB >> 12, s0 = mB & 4095;
      f32x4 a = acc[mt][nt];
      if (z == 2) {
        ushort4 o;
        o.x = f2bf(a[0] + bb); o.y = f2bf(a[1] + bb);
        o.z = f2bf(a[2] + bb); o.w = f2bf(a[3] + bb);
        // permuted storage column: (32K|16A|4G|B) -> (32K|8G|4A|B); B=0 here
        int scol = (s0 & ~31) | (((s0 >> 2) & 3) << 3) | (((s0 >> 4) & 1) << 2);
        *(ushort4*)&Vt[((size_t)((bidx * NH + head) * 64 + d)) * SEQ + scol] = o;
      } else {
        ushort_t* dst = (z == 0) ? Qh : Kh;
        float sc = (z == 0) ? QSCALE : 1.0f;
        size_t base = (size_t)(bidx * NH + head) * SEQ;
#pragma unroll
        for (int i = 0; i < 4; ++i)
          dst[(base + s0 + i) * 64 + d] = f2bf((a[i] + bb) * sc);
      }
    }
  }
}

// ---------------------------------------------------------------- kernel 4
// Flash attention, no-max softmax, zero-shuffle P, 8-wave blocks (4qh x 2kh).
// Round-9 structure: q-tile per block stays 128 (grid 768 -> total staging
// identical to round 6; round 8's regression was doubled staging), but 8
// waves split it 4-ways in q and 2-ways in k: per-wave serial chain is the
// short round-8 one (4 ak + 4 av reads, 18 MFMA, 16 exp2) while 2-3 resident
// blocks now give 4-6 waves/SIMD of latency hiding (round-7 lesson inverted).
// All addresses are the validated round-6 forms restricted to one k-half.
// Epilogue: kh=1 waves push partial O through the drained K/V LDS buffers
// (l through a 2KB side array); kh=0 waves add + store.
// Sync discipline (validated round 6): per-wave vmcnt(0) drain before every
// handoff barrier; no staging issued on the last iteration.
__global__ __launch_bounds__(512, 4) void attn_kernel(const ushort_t* __restrict__ Qh,
                                                      const ushort_t* __restrict__ Kh,
                                                      const ushort_t* __restrict__ Vt,
                                                      float* __restrict__ out) {
  const int bh = blockIdx.y;
  const int b = bh / NH, head = bh - b * NH;
  const int t = threadIdx.x, w = t >> 6, lane = t & 63;
  const int g = lane >> 4, qc = lane & 15;
  const int qh = w >> 1, kh = w & 1;
  const ushort_t* Qb = Qh + (size_t)bh * SEQ * 64;
  const ushort_t* Kb = Kh + (size_t)bh * SEQ * 64;
  const ushort_t* Vb = Vt + (size_t)bh * 64 * SEQ;
  const int q0 = blockIdx.x * 128 + qh * 32;

  __shared__ ushort_t Kls[2][4096];  // [buf][64 krow x 64 d], (r&7)-swizzled 16B chunks
  __shared__ ushort_t Vls[2][4096];  // [buf][64 d x 64 k],   (r&7)-swizzled 16B chunks
  __shared__ float    redL[512];     // cross-kh l partials

  // staging map: 512 threads x 1 chunk each (16B) per tile
  const int jr = t >> 3;
  const int jc = (t & 7) ^ (jr & 7);

  bfrag qv[2][2];
#pragma unroll
  for (int qf = 0; qf < 2; ++qf)
#pragma unroll
    for (int dd = 0; dd < 2; ++dd)
      qv[qf][dd] = *(const bfrag*)&Qb[(size_t)(q0 + qf * 16 + qc) * 64 + dd * 32 + g * 8];

  f32x4 o[2][4];
  f32x4 lacc[2];
#pragma unroll
  for (int qf = 0; qf < 2; ++qf) {
    lacc[qf] = zero4();
#pragma unroll
    for (int dt = 0; dt < 4; ++dt) o[qf][dt] = zero4();
  }
  bfrag ones;
#pragma unroll
  for (int j = 0; j < 8; ++j) ones[j] = (__bf16)1.0f;

  // prologue: stage tile 0 into buf 0 (one K + one V chunk per thread)
  gload_lds16(&Kb[(size_t)jr * 64 + jc * 8], &Kls[0][w * 512]);
  gload_lds16(&Vb[(size_t)jr * SEQ + jc * 8], &Vls[0][w * 512]);

  for (int kt = 0; kt < 64; ++kt) {
    const int cur = kt & 1;
    DRAIN_VMEM();     // THIS wave's staging (prev iter / prologue) has landed
    __syncthreads();  // ... and now everyone's has: buf `cur` fully staged
    if (kt < 63) {    // no staging on last iter: nothing in flight at s_endpgm
      const int kbn = (kt + 1) * 64;
      gload_lds16(&Kb[(size_t)(kbn + jr) * 64 + jc * 8], &Kls[cur ^ 1][w * 512]);
      gload_lds16(&Vb[(size_t)jr * SEQ + kbn + jc * 8], &Vls[cur ^ 1][w * 512]);
    }
    const ushort_t* Kc = Kls[cur];
    const ushort_t* Vc = Vls[cur];

    // K fragments: this wave's 32-k half (rows kh*32 + s*16 + qc)
    bfrag ak[2][2];
#pragma unroll
    for (int s = 0; s < 2; ++s) {
      const int r = kh * 32 + s * 16 + qc;
      ak[s][0] = *(const bfrag*)&Kc[r * 64 + ((g ^ (qc & 7)) * 8)];
      ak[s][1] = *(const bfrag*)&Kc[r * 64 + (((4 + g) ^ (qc & 7)) * 8)];
    }
    // V fragments: this wave's 32-k half of all 64 d rows
    bfrag av[4];
#pragma unroll
    for (int dt = 0; dt < 4; ++dt)
      av[dt] = *(const bfrag*)&Vc[(dt * 16 + qc) * 64 + (((kh * 4 + g) ^ (qc & 7)) * 8)];

    // S^T slabs -> P fragment (one per qf; k-order matches V scol permutation)
    bfrag bpq[2];
#pragma unroll
    for (int qf = 0; qf < 2; ++qf) {
      f32x4 st[2];
      __builtin_amdgcn_s_setprio(1);
#pragma unroll
      for (int s = 0; s < 2; ++s) {
        f32x4 zz = zero4();
        zz = MFMA16(ak[s][0], qv[qf][0], zz);
        st[s] = MFMA16(ak[s][1], qv[qf][1], zz);
      }
      __builtin_amdgcn_s_setprio(0);
      bfrag p;
#pragma unroll
      for (int i = 0; i < 4; ++i) {
        p[i]     = (__bf16)__builtin_amdgcn_exp2f(st[0][i]);
        p[4 + i] = (__bf16)__builtin_amdgcn_exp2f(st[1][i]);
      }
      bpq[qf] = p;
      lacc[qf] = MFMA16(ones, p, lacc[qf]);
    }

    // O^T += Vperm.P^T  (partial over this wave's k-half)
    __builtin_amdgcn_s_setprio(1);
#pragma unroll
    for (int dt = 0; dt < 4; ++dt) {
      o[0][dt] = MFMA16(av[dt], bpq[0], o[0][dt]);
      o[1][dt] = MFMA16(av[dt], bpq[1], o[1][dt]);
    }
    __builtin_amdgcn_s_setprio(0);
  }

  // ---- cross-kh reduction through LDS (K/V buffers idle + DMA drained) ----
  // redO: 4 qh x 2 qf x 4 dt x 64 lanes x f32x4 = 32KB spanning Kls then Vls.
  __syncthreads();
  float* redK = (float*)&Kls[0][0];  // qh 0,1
  float* redV = (float*)&Vls[0][0];  // qh 2,3
  float* redO = (qh < 2) ? redK : redV;
  const int ro = (((qh & 1) * 2) * 4) * 256;  // base for qf=0,dt=0 of this qh
  if (kh == 1) {
#pragma unroll
    for (int qf = 0; qf < 2; ++qf) {
#pragma unroll
      for (int dt = 0; dt < 4; ++dt)
        *(f32x4*)&redO[ro + (qf * 4 + dt) * 256 + lane * 4] = o[qf][dt];
      redL[qh * 128 + qf * 64 + lane] = lacc[qf][0];
    }
  }
  __syncthreads();
  if (kh == 0) {
#pragma unroll
    for (int qf = 0; qf < 2; ++qf) {
      float l = lacc[qf][0] + redL[qh * 128 + qf * 64 + lane];
      float inv = 1.0f / l;
      int qrow = q0 + qf * 16 + qc;
      float* orow = out + (size_t)(b * SEQ + qrow) * HID + head * 64;
#pragma unroll
      for (int dt = 0; dt < 4; ++dt) {
        f32x4 p = *(f32x4*)&redO[ro + (qf * 4 + dt) * 256 + lane * 4];
        f32x4 s = o[qf][dt] + p;
        float4 vv;
        vv.x = s[0] * inv; vv.y = s[1] * inv; vv.z = s[2] * inv; vv.w = s[3] * inv;
        *(float4*)(orow + dt * 16 + 4 * g) = vv;
      }
    }
  }
}

// ---------------------------------------------------------------- launch
extern "C" void kernel_launch(void* const* d_in, const int* in_sizes, int n_in,
                              void* d_out, int out_size, void* d_ws, size_t ws_size,
                              hipStream_t stream) {
  (void)in_sizes; (void)n_in; (void)out_size; (void)ws_size;
  const float* hs = (const float*)d_in[0];
  const float* Wq = (const float*)d_in[1];
  const float* bq = (const float*)d_in[2];
  const float* Wk = (const float*)d_in[3];
  const float* bk = (const float*)d_in[4];
  const float* Wv = (const float*)d_in[5];
  const float* bv = (const float*)d_in[6];
  float* out = (float*)d_out;

  char* ws = (char*)d_ws;
  ushort_t* Abf = (ushort_t*)ws;                               // 12582912 B
  ushort_t* Wt  = (ushort_t*)(ws + 12582912);                  //  3538944 B
  ushort_t* Qh  = (ushort_t*)(ws + 12582912 + 3538944);        // 12582912 B
  ushort_t* Kh  = Qh + 6291456;
  ushort_t* Vt  = Kh + 6291456;

  cvt_hidden<<<6144, 256, 0, stream>>>(hs, Abf);
  transpose_w<<<dim3(12, 12, 3), 256, 0, stream>>>(Wq, Wk, Wv, Wt);
  qkv_gemm<<<dim3(64, 6, 3), 256, 0, stream>>>(Abf, Wt, bq, bk, bv, Qh, Kh, Vt);
  attn_kernel<<<dim3(32, 24), 512, 0, stream>>>(Qh, Kh, Vt, out);
}